// Round 9
// baseline (149.863 us; speedup 1.0000x reference)
//
#include <hip/hip_runtime.h>

#define FDIM 512
#define S_ELEMS (FDIM * FDIM)
#define NB 256                 // batches
#define GROUPS 4
#define BPG (NB / GROUPS)      // 64 batches (64 MB of Sigma) per group

// ---------------- ws layout (floats) ----------------
#define R_OFF      0                          // r[256][512]
#define CP_OFF     (NB * FDIM)                // c_part[256*8][512]
#define WS_FLOATS  (NB * FDIM + NB * 8 * FDIM)

__device__ __forceinline__ float4 ld4(const float* p) { return *(const float4*)p; }

typedef float vf4 __attribute__((ext_vector_type(4)));
__device__ __forceinline__ void st4nt(float* p, float4 v) {
    __builtin_nontemporal_store(*(vf4*)&v, (vf4*)p);
}

// ======================= K1: p, r, c-partials (pure read) ==============
// grid 512 = 64 batches x 8 slabs(64 rows). block 256 thr = 4 waves.
// Wave w streams 16 rows with a 4-row-deep named-register pipeline.
__global__ __launch_bounds__(256)
void k1_rc(const float* __restrict__ mu,
           const float* __restrict__ Sigma,
           float* __restrict__ p_out,
           float* __restrict__ ws,
           int b0) {
    const int bid  = blockIdx.x;
    const int b    = b0 + (bid >> 3);
    const int slab = bid & 7;
    const int t = threadIdx.x;
    const int w = t >> 6;
    const int l = t & 63;

    __shared__ __align__(16) float p_lds[FDIM];
    __shared__ __align__(16) float cred[4][FDIM];
    __shared__ float red[4];
    __shared__ float sc[1];

    // --- softmax p[b,:], 2 elems/thread ---
    const float x0 = mu[(size_t)b * FDIM + t];
    const float x1 = mu[(size_t)b * FDIM + t + 256];
    float m = fmaxf(x0, x1);
    #pragma unroll
    for (int off = 32; off >= 1; off >>= 1) m = fmaxf(m, __shfl_xor(m, off));
    if (l == 0) red[w] = m;
    __syncthreads();
    if (t == 0) sc[0] = fmaxf(fmaxf(red[0], red[1]), fmaxf(red[2], red[3]));
    __syncthreads();
    const float mx = sc[0];
    const float e0 = __expf(x0 - mx);
    const float e1 = __expf(x1 - mx);
    float ssum = e0 + e1;
    #pragma unroll
    for (int off = 32; off >= 1; off >>= 1) ssum += __shfl_xor(ssum, off);
    if (l == 0) red[w] = ssum;
    __syncthreads();
    if (t == 0) sc[0] = red[0] + red[1] + red[2] + red[3];
    __syncthreads();
    const float inv = 1.0f / sc[0];
    const float pva = e0 * inv, pvb = e1 * inv;
    p_lds[t] = pva;
    p_lds[t + 256] = pvb;
    if (slab == 0) {
        p_out[(size_t)b * FDIM + t] = pva;
        p_out[(size_t)b * FDIM + t + 256] = pvb;
    }
    __syncthreads();

    const float4 p0 = ld4(&p_lds[4 * l]);
    const float4 p1 = ld4(&p_lds[256 + 4 * l]);

    const int i0 = slab * 64 + w * 16;                 // first global row
    const float* base = Sigma + (size_t)b * S_ELEMS + (size_t)i0 * FDIM + 4 * l;
    float* r_ws = ws + R_OFF + (size_t)b * FDIM;

    float4 c0 = make_float4(0.f, 0.f, 0.f, 0.f);
    float4 c1 = make_float4(0.f, 0.f, 0.f, 0.f);
    float4 A0, A1, B0, B1, C0, C1, D0, D1;

#define LD1(P, q) do { const float* gp_ = base + (size_t)(q) * FDIM;        \
    P##0 = ld4(gp_); P##1 = ld4(gp_ + 256); } while (0)

#define RCROW(v0, v1, q) do {                                               \
    const int i_ = i0 + (q);                                                \
    float dot = v0.x*p0.x + v0.y*p0.y + v0.z*p0.z + v0.w*p0.w               \
              + v1.x*p1.x + v1.y*p1.y + v1.z*p1.z + v1.w*p1.w;              \
    _Pragma("unroll")                                                       \
    for (int o_ = 32; o_ >= 1; o_ >>= 1) dot += __shfl_xor(dot, o_);        \
    if (l == 0) r_ws[i_] = dot;                                             \
    const float pi_ = p_lds[i_];                                            \
    c0.x += pi_*v0.x; c0.y += pi_*v0.y; c0.z += pi_*v0.z; c0.w += pi_*v0.w; \
    c1.x += pi_*v1.x; c1.y += pi_*v1.y; c1.z += pi_*v1.z; c1.w += pi_*v1.w; \
} while (0)
#define RC1(P, q) RCROW(P##0, P##1, q)

    LD1(A, 0); LD1(B, 1); LD1(C, 2);
    RC1(A, 0);  LD1(D, 3);
    RC1(B, 1);  LD1(A, 4);
    RC1(C, 2);  LD1(B, 5);
    RC1(D, 3);  LD1(C, 6);
    RC1(A, 4);  LD1(D, 7);
    RC1(B, 5);  LD1(A, 8);
    RC1(C, 6);  LD1(B, 9);
    RC1(D, 7);  LD1(C, 10);
    RC1(A, 8);  LD1(D, 11);
    RC1(B, 9);  LD1(A, 12);
    RC1(C, 10); LD1(B, 13);
    RC1(D, 11); LD1(C, 14);
    RC1(A, 12); LD1(D, 15);
    RC1(B, 13);
    RC1(C, 14);
    RC1(D, 15);
#undef LD1
#undef RCROW
#undef RC1

    // --- reduce c partials across the 4 waves ---
    *(float4*)&cred[w][4 * l] = c0;
    *(float4*)&cred[w][256 + 4 * l] = c1;
    __syncthreads();
    const float ca = cred[0][t] + cred[1][t] + cred[2][t] + cred[3][t];
    const float cb = cred[0][t + 256] + cred[1][t + 256] + cred[2][t + 256] + cred[3][t + 256];
    float* cp = ws + CP_OFF + ((size_t)b * 8 + slab) * FDIM;
    cp[t] = ca;
    cp[t + 256] = cb;
}

// ======================= K3: output stream (reverse, NT stores) ========
// grid 512 REVERSED within group; block 256 thr = 4 waves, 16 rows/wave.
// c and s recomputed per-block from ws partials (K2b folded in).
__global__ __launch_bounds__(256)
void k3_out(const float* __restrict__ Sigma,
            const float* __restrict__ p_out,
            const float* __restrict__ ws,
            float* __restrict__ S_out,
            int b0) {
    const int bid  = 511 - (int)blockIdx.x;    // reverse sweep within group
    const int b    = b0 + (bid >> 3);
    const int slab = bid & 7;
    const int t = threadIdx.x;
    const int w = t >> 6;
    const int l = t & 63;

    __shared__ __align__(16) float c_lds[FDIM];
    __shared__ float pr[64], rr[64];
    __shared__ float red[4];
    __shared__ float s_sh;

    const int i0 = slab * 64 + w * 16;
    const float* base = Sigma + (size_t)b * S_ELEMS + (size_t)i0 * FDIM + 4 * l;
    float* obase      = S_out + (size_t)b * S_ELEMS + (size_t)i0 * FDIM + 4 * l;

    float4 A0, A1, B0, B1, C0, C1, D0, D1;

#define LD3(P, q) do { const float* gp_ = base + (size_t)(q) * FDIM;        \
    P##0 = ld4(gp_); P##1 = ld4(gp_ + 256); } while (0)

    // Issue the first three row-groups immediately; they fly during prologue.
    LD3(A, 0); LD3(B, 1); LD3(C, 2);

    // --- prologue: c = sum of 8 partials; s = p.r; slab-local p,r ---
    const float* cp = ws + CP_OFF + (size_t)b * 8 * FDIM;
    float ca = 0.f, cb = 0.f;
    #pragma unroll
    for (int j = 0; j < 8; ++j) {
        ca += cp[(size_t)j * FDIM + t];
        cb += cp[(size_t)j * FDIM + t + 256];
    }
    c_lds[t] = ca;
    c_lds[t + 256] = cb;

    const float* pb_g = p_out + (size_t)b * FDIM;
    const float* rb_g = ws + R_OFF + (size_t)b * FDIM;
    const float pv0 = pb_g[t], pv1 = pb_g[t + 256];
    const float rv0 = rb_g[t], rv1 = rb_g[t + 256];
    float sv = pv0 * rv0 + pv1 * rv1;
    #pragma unroll
    for (int off = 32; off >= 1; off >>= 1) sv += __shfl_xor(sv, off);
    if (l == 0) red[w] = sv;
    if (t < 64) {
        pr[t] = pb_g[slab * 64 + t];
        rr[t] = rb_g[slab * 64 + t];
    }
    __syncthreads();
    if (t == 0) s_sh = red[0] + red[1] + red[2] + red[3];
    __syncthreads();
    const float s = s_sh;
    const float4 p0 = ld4(pb_g + 4 * l);
    const float4 p1 = ld4(pb_g + 256 + 4 * l);
    const float4 c0 = ld4(&c_lds[4 * l]);
    const float4 c1 = ld4(&c_lds[256 + 4 * l]);

#define OWROW(v0, v1, q) do {                                               \
    const int lr_ = w * 16 + (q);                                           \
    const float pi_ = pr[lr_];                                              \
    const float f_  = s - rr[lr_];                                          \
    float4 o0, o1;                                                          \
    o0.x = pi_*p0.x*(v0.x + (f_ - c0.x));                                   \
    o0.y = pi_*p0.y*(v0.y + (f_ - c0.y));                                   \
    o0.z = pi_*p0.z*(v0.z + (f_ - c0.z));                                   \
    o0.w = pi_*p0.w*(v0.w + (f_ - c0.w));                                   \
    o1.x = pi_*p1.x*(v1.x + (f_ - c1.x));                                   \
    o1.y = pi_*p1.y*(v1.y + (f_ - c1.y));                                   \
    o1.z = pi_*p1.z*(v1.z + (f_ - c1.z));                                   \
    o1.w = pi_*p1.w*(v1.w + (f_ - c1.w));                                   \
    float* op_ = obase + (size_t)(q) * FDIM;                                \
    st4nt(op_, o0); st4nt(op_ + 256, o1);                                   \
} while (0)
#define OW3(P, q) OWROW(P##0, P##1, q)

    OW3(A, 0);  LD3(D, 3);
    OW3(B, 1);  LD3(A, 4);
    OW3(C, 2);  LD3(B, 5);
    OW3(D, 3);  LD3(C, 6);
    OW3(A, 4);  LD3(D, 7);
    OW3(B, 5);  LD3(A, 8);
    OW3(C, 6);  LD3(B, 9);
    OW3(D, 7);  LD3(C, 10);
    OW3(A, 8);  LD3(D, 11);
    OW3(B, 9);  LD3(A, 12);
    OW3(C, 10); LD3(B, 13);
    OW3(D, 11); LD3(C, 14);
    OW3(A, 12); LD3(D, 15);
    OW3(B, 13);
    OW3(C, 14);
    OW3(D, 15);
#undef LD3
#undef OWROW
#undef OW3
}

// ======================= fallback: round-1 fused (proven) ========
__global__ __launch_bounds__(1024, 1)
void rvsoftmax_fused(const float* __restrict__ mu,
                     const float* __restrict__ Sigma,
                     float* __restrict__ p_out,
                     float* __restrict__ S_out) {
    const int b = blockIdx.x, t = threadIdx.x, w = t >> 6, l = t & 63;
    __shared__ __align__(16) float p_lds[FDIM];
    __shared__ __align__(16) float r_lds[FDIM];
    __shared__ __align__(16) float c_lds[FDIM];
    __shared__ __align__(16) float c_stage[16][FDIM];
    __shared__ float red[16]; __shared__ float sc[2];
    float x = (t < FDIM) ? mu[(size_t)b * FDIM + t] : -__builtin_inff();
    float m = x;
    #pragma unroll
    for (int off = 32; off >= 1; off >>= 1) m = fmaxf(m, __shfl_xor(m, off));
    if (l == 0) red[w] = m;
    __syncthreads();
    if (t == 0) { float mm = red[0]; for (int j = 1; j < 16; ++j) mm = fmaxf(mm, red[j]); sc[0] = mm; }
    __syncthreads();
    const float mx = sc[0];
    float e = (t < FDIM) ? __expf(x - mx) : 0.f;
    float ssum = e;
    #pragma unroll
    for (int off = 32; off >= 1; off >>= 1) ssum += __shfl_xor(ssum, off);
    if (l == 0) red[w] = ssum;
    __syncthreads();
    if (t == 0) { float tt = 0.f; for (int j = 0; j < 16; ++j) tt += red[j]; sc[0] = tt; }
    __syncthreads();
    const float inv = 1.0f / sc[0];
    if (t < FDIM) { float pv = e * inv; p_lds[t] = pv; p_out[(size_t)b * FDIM + t] = pv; }
    __syncthreads();
    const float* Sb = Sigma + (size_t)b * S_ELEMS;
    const float4 p0 = ld4(&p_lds[4 * l]);
    const float4 p1 = ld4(&p_lds[256 + 4 * l]);
    float4 c0 = make_float4(0.f, 0.f, 0.f, 0.f), c1 = make_float4(0.f, 0.f, 0.f, 0.f);
    for (int j = 0; j < 32; ++j) {
        const int i = j * 16 + w;
        const float* row = Sb + (size_t)i * FDIM;
        const float4 a0 = ld4(&row[4 * l]); const float4 a1 = ld4(&row[256 + 4 * l]);
        const float pi = p_lds[i];
        float dot = a0.x*p0.x + a0.y*p0.y + a0.z*p0.z + a0.w*p0.w
                  + a1.x*p1.x + a1.y*p1.y + a1.z*p1.z + a1.w*p1.w;
        #pragma unroll
        for (int off = 32; off >= 1; off >>= 1) dot += __shfl_xor(dot, off);
        if (l == 0) r_lds[i] = dot;
        c0.x += pi*a0.x; c0.y += pi*a0.y; c0.z += pi*a0.z; c0.w += pi*a0.w;
        c1.x += pi*a1.x; c1.y += pi*a1.y; c1.z += pi*a1.z; c1.w += pi*a1.w;
    }
    *(float4*)&c_stage[w][4 * l] = c0;
    *(float4*)&c_stage[w][256 + 4 * l] = c1;
    __syncthreads();
    if (t < FDIM) {
        float cc = 0.f;
        #pragma unroll
        for (int j = 0; j < 16; ++j) cc += c_stage[j][t];
        c_lds[t] = cc;
    }
    __syncthreads();
    float sv = (t < FDIM) ? p_lds[t] * r_lds[t] : 0.f;
    #pragma unroll
    for (int off = 32; off >= 1; off >>= 1) sv += __shfl_xor(sv, off);
    if (l == 0) red[w] = sv;
    __syncthreads();
    if (t == 0) { float tt = 0.f; for (int j = 0; j < 16; ++j) tt += red[j]; sc[1] = tt; }
    __syncthreads();
    const float s = sc[1];
    const float4 cc0 = ld4(&c_lds[4 * l]); const float4 cc1 = ld4(&c_lds[256 + 4 * l]);
    float* Ob = S_out + (size_t)b * S_ELEMS;
    for (int j = 31; j >= 0; --j) {
        const int i = j * 16 + w;
        const float* row = Sb + (size_t)i * FDIM;
        float* orow = Ob + (size_t)i * FDIM;
        const float4 a0 = ld4(&row[4 * l]); const float4 a1 = ld4(&row[256 + 4 * l]);
        const float pi = p_lds[i];
        const float f = s - r_lds[i];
        float4 o0, o1;
        o0.x = pi*p0.x*(a0.x + (f - cc0.x)); o0.y = pi*p0.y*(a0.y + (f - cc0.y));
        o0.z = pi*p0.z*(a0.z + (f - cc0.z)); o0.w = pi*p0.w*(a0.w + (f - cc0.w));
        o1.x = pi*p1.x*(a1.x + (f - cc1.x)); o1.y = pi*p1.y*(a1.y + (f - cc1.y));
        o1.z = pi*p1.z*(a1.z + (f - cc1.z)); o1.w = pi*p1.w*(a1.w + (f - cc1.w));
        *(float4*)&orow[4 * l] = o0;
        *(float4*)&orow[256 + 4 * l] = o1;
    }
}

extern "C" void kernel_launch(void* const* d_in, const int* in_sizes, int n_in,
                              void* d_out, int out_size, void* d_ws, size_t ws_size,
                              hipStream_t stream) {
    (void)in_sizes; (void)n_in; (void)out_size;
    const float* mu    = (const float*)d_in[0];
    const float* Sigma = (const float*)d_in[1];
    float* p_out = (float*)d_out;
    float* S_out = (float*)d_out + (size_t)NB * FDIM;

    if (ws_size >= (size_t)WS_FLOATS * sizeof(float)) {
        float* ws = (float*)d_ws;
        for (int g = 0; g < GROUPS; ++g) {
            hipLaunchKernelGGL(k1_rc,  dim3(BPG * 8), dim3(256), 0, stream,
                               mu, Sigma, p_out, ws, g * BPG);
            hipLaunchKernelGGL(k3_out, dim3(BPG * 8), dim3(256), 0, stream,
                               Sigma, p_out, ws, S_out, g * BPG);
        }
    } else {
        hipLaunchKernelGGL(rvsoftmax_fused, dim3(NB), dim3(1024), 0, stream,
                           mu, Sigma, p_out, S_out);
    }
}

// Round 10
// 142.154 us; speedup vs baseline: 1.0542x; 1.0542x over previous
//
#include <hip/hip_runtime.h>

#define FDIM 512
#define S_ELEMS (FDIM * FDIM)
#define NB 256
#define HALF_B 128                 // batches per group (GROUPS=2)
#define HALF_BLOCKS (HALF_B * 8)   // 1024 blocks per role

// ---------------- ws layout (floats) ----------------
#define R_OFF      0                          // r[256][512]
#define CP_OFF     (NB * FDIM)                // c_part[256*8][512]
#define WS_FLOATS  (NB * FDIM + NB * 8 * FDIM)

__device__ __forceinline__ float4 ld4(const float* p) { return *(const float4*)p; }

typedef float vf4 __attribute__((ext_vector_type(4)));
__device__ __forceinline__ void st4nt(float* p, float4 v) {
    __builtin_nontemporal_store(*(vf4*)&v, (vf4*)p);
}

// ======================= K1 body: p, r, c-partials (pure read) =========
// One block = (batch b, slab of 64 rows). 256 thr = 4 waves; wave streams
// 16 rows, 4-row-deep named-register pipeline.
__device__ __forceinline__ void k1_body(const float* __restrict__ mu,
                                        const float* __restrict__ Sigma,
                                        float* __restrict__ p_out,
                                        float* __restrict__ ws,
                                        int b, int slab) {
    const int t = threadIdx.x;
    const int w = t >> 6;
    const int l = t & 63;

    __shared__ __align__(16) float p_lds1[FDIM];
    __shared__ __align__(16) float cred1[4][FDIM];
    __shared__ float red1[4];
    __shared__ float sc1;

    // --- softmax p[b,:], 2 elems/thread ---
    const float x0 = mu[(size_t)b * FDIM + t];
    const float x1 = mu[(size_t)b * FDIM + t + 256];
    float m = fmaxf(x0, x1);
    #pragma unroll
    for (int off = 32; off >= 1; off >>= 1) m = fmaxf(m, __shfl_xor(m, off));
    if (l == 0) red1[w] = m;
    __syncthreads();
    if (t == 0) sc1 = fmaxf(fmaxf(red1[0], red1[1]), fmaxf(red1[2], red1[3]));
    __syncthreads();
    const float mx = sc1;
    const float e0 = __expf(x0 - mx);
    const float e1 = __expf(x1 - mx);
    float ssum = e0 + e1;
    #pragma unroll
    for (int off = 32; off >= 1; off >>= 1) ssum += __shfl_xor(ssum, off);
    if (l == 0) red1[w] = ssum;
    __syncthreads();
    if (t == 0) sc1 = red1[0] + red1[1] + red1[2] + red1[3];
    __syncthreads();
    const float inv = 1.0f / sc1;
    const float pva = e0 * inv, pvb = e1 * inv;
    p_lds1[t] = pva;
    p_lds1[t + 256] = pvb;
    if (slab == 0) {
        p_out[(size_t)b * FDIM + t] = pva;
        p_out[(size_t)b * FDIM + t + 256] = pvb;
    }
    __syncthreads();

    const float4 p0 = ld4(&p_lds1[4 * l]);
    const float4 p1 = ld4(&p_lds1[256 + 4 * l]);

    const int i0 = slab * 64 + w * 16;
    const float* base = Sigma + (size_t)b * S_ELEMS + (size_t)i0 * FDIM + 4 * l;
    float* r_ws = ws + R_OFF + (size_t)b * FDIM;

    float4 c0 = make_float4(0.f, 0.f, 0.f, 0.f);
    float4 c1 = make_float4(0.f, 0.f, 0.f, 0.f);
    float4 A0, A1, B0, B1, C0, C1, D0, D1;

#define LD1(P, q) do { const float* gp_ = base + (size_t)(q) * FDIM;        \
    P##0 = ld4(gp_); P##1 = ld4(gp_ + 256); } while (0)

#define RCROW(v0, v1, q) do {                                               \
    const int i_ = i0 + (q);                                                \
    float dot = v0.x*p0.x + v0.y*p0.y + v0.z*p0.z + v0.w*p0.w               \
              + v1.x*p1.x + v1.y*p1.y + v1.z*p1.z + v1.w*p1.w;              \
    _Pragma("unroll")                                                       \
    for (int o_ = 32; o_ >= 1; o_ >>= 1) dot += __shfl_xor(dot, o_);        \
    if (l == 0) r_ws[i_] = dot;                                             \
    const float pi_ = p_lds1[i_];                                           \
    c0.x += pi_*v0.x; c0.y += pi_*v0.y; c0.z += pi_*v0.z; c0.w += pi_*v0.w; \
    c1.x += pi_*v1.x; c1.y += pi_*v1.y; c1.z += pi_*v1.z; c1.w += pi_*v1.w; \
} while (0)
#define RC1(P, q) RCROW(P##0, P##1, q)

    LD1(A, 0); LD1(B, 1); LD1(C, 2);
    RC1(A, 0);  LD1(D, 3);
    RC1(B, 1);  LD1(A, 4);
    RC1(C, 2);  LD1(B, 5);
    RC1(D, 3);  LD1(C, 6);
    RC1(A, 4);  LD1(D, 7);
    RC1(B, 5);  LD1(A, 8);
    RC1(C, 6);  LD1(B, 9);
    RC1(D, 7);  LD1(C, 10);
    RC1(A, 8);  LD1(D, 11);
    RC1(B, 9);  LD1(A, 12);
    RC1(C, 10); LD1(B, 13);
    RC1(D, 11); LD1(C, 14);
    RC1(A, 12); LD1(D, 15);
    RC1(B, 13);
    RC1(C, 14);
    RC1(D, 15);
#undef LD1
#undef RCROW
#undef RC1

    // --- reduce c partials across the 4 waves ---
    *(float4*)&cred1[w][4 * l] = c0;
    *(float4*)&cred1[w][256 + 4 * l] = c1;
    __syncthreads();
    const float ca = cred1[0][t] + cred1[1][t] + cred1[2][t] + cred1[3][t];
    const float cb = cred1[0][t + 256] + cred1[1][t + 256] + cred1[2][t + 256] + cred1[3][t + 256];
    float* cp = ws + CP_OFF + ((size_t)b * 8 + slab) * FDIM;
    cp[t] = ca;
    cp[t + 256] = cb;
}

// ======================= K3 body: output stream (NT stores) ============
__device__ __forceinline__ void k3_body(const float* __restrict__ Sigma,
                                        const float* __restrict__ p_out,
                                        const float* __restrict__ ws,
                                        float* __restrict__ S_out,
                                        int b, int slab) {
    const int t = threadIdx.x;
    const int w = t >> 6;
    const int l = t & 63;

    __shared__ __align__(16) float c_lds3[FDIM];
    __shared__ float pr3[64], rr3[64];
    __shared__ float red3[4];
    __shared__ float s_sh3;

    const int i0 = slab * 64 + w * 16;
    const float* base = Sigma + (size_t)b * S_ELEMS + (size_t)i0 * FDIM + 4 * l;
    float* obase      = S_out + (size_t)b * S_ELEMS + (size_t)i0 * FDIM + 4 * l;

    float4 A0, A1, B0, B1, C0, C1, D0, D1;

#define LD3(P, q) do { const float* gp_ = base + (size_t)(q) * FDIM;        \
    P##0 = ld4(gp_); P##1 = ld4(gp_ + 256); } while (0)

    // Issue the first three row-groups; they fly during the prologue.
    LD3(A, 0); LD3(B, 1); LD3(C, 2);

    // --- prologue: c = sum of 8 partials; s = p.r; slab-local p,r ---
    const float* cp = ws + CP_OFF + (size_t)b * 8 * FDIM;
    float ca = 0.f, cb = 0.f;
    #pragma unroll
    for (int j = 0; j < 8; ++j) {
        ca += cp[(size_t)j * FDIM + t];
        cb += cp[(size_t)j * FDIM + t + 256];
    }
    c_lds3[t] = ca;
    c_lds3[t + 256] = cb;

    const float* pb_g = p_out + (size_t)b * FDIM;
    const float* rb_g = ws + R_OFF + (size_t)b * FDIM;
    const float pv0 = pb_g[t], pv1 = pb_g[t + 256];
    const float rv0 = rb_g[t], rv1 = rb_g[t + 256];
    float sv = pv0 * rv0 + pv1 * rv1;
    #pragma unroll
    for (int off = 32; off >= 1; off >>= 1) sv += __shfl_xor(sv, off);
    if (l == 0) red3[w] = sv;
    if (t < 64) {
        pr3[t] = pb_g[slab * 64 + t];
        rr3[t] = rb_g[slab * 64 + t];
    }
    __syncthreads();
    if (t == 0) s_sh3 = red3[0] + red3[1] + red3[2] + red3[3];
    __syncthreads();
    const float s = s_sh3;
    const float4 p0 = ld4(pb_g + 4 * l);
    const float4 p1 = ld4(pb_g + 256 + 4 * l);
    const float4 c0 = ld4(&c_lds3[4 * l]);
    const float4 c1 = ld4(&c_lds3[256 + 4 * l]);

#define OWROW(v0, v1, q) do {                                               \
    const int lr_ = w * 16 + (q);                                           \
    const float pi_ = pr3[lr_];                                             \
    const float f_  = s - rr3[lr_];                                         \
    float4 o0, o1;                                                          \
    o0.x = pi_*p0.x*(v0.x + (f_ - c0.x));                                   \
    o0.y = pi_*p0.y*(v0.y + (f_ - c0.y));                                   \
    o0.z = pi_*p0.z*(v0.z + (f_ - c0.z));                                   \
    o0.w = pi_*p0.w*(v0.w + (f_ - c0.w));                                   \
    o1.x = pi_*p1.x*(v1.x + (f_ - c1.x));                                   \
    o1.y = pi_*p1.y*(v1.y + (f_ - c1.y));                                   \
    o1.z = pi_*p1.z*(v1.z + (f_ - c1.z));                                   \
    o1.w = pi_*p1.w*(v1.w + (f_ - c1.w));                                   \
    float* op_ = obase + (size_t)(q) * FDIM;                                \
    st4nt(op_, o0); st4nt(op_ + 256, o1);                                   \
} while (0)
#define OW3(P, q) OWROW(P##0, P##1, q)

    OW3(A, 0);  LD3(D, 3);
    OW3(B, 1);  LD3(A, 4);
    OW3(C, 2);  LD3(B, 5);
    OW3(D, 3);  LD3(C, 6);
    OW3(A, 4);  LD3(D, 7);
    OW3(B, 5);  LD3(A, 8);
    OW3(C, 6);  LD3(B, 9);
    OW3(D, 7);  LD3(C, 10);
    OW3(A, 8);  LD3(D, 11);
    OW3(B, 9);  LD3(A, 12);
    OW3(C, 10); LD3(B, 13);
    OW3(D, 11); LD3(C, 14);
    OW3(A, 12); LD3(D, 15);
    OW3(B, 13);
    OW3(C, 14);
    OW3(D, 15);
#undef LD3
#undef OWROW
#undef OW3
}

// ======================= kernels =======================
__global__ __launch_bounds__(256)
void k1_kernel(const float* __restrict__ mu, const float* __restrict__ Sigma,
               float* __restrict__ p_out, float* __restrict__ ws, int b0) {
    const int bid = blockIdx.x;
    k1_body(mu, Sigma, p_out, ws, b0 + (bid >> 3), bid & 7);
}

__global__ __launch_bounds__(256)
void k3_kernel(const float* __restrict__ Sigma, const float* __restrict__ p_out,
               const float* __restrict__ ws, float* __restrict__ S_out, int b0) {
    const int bid = (int)gridDim.x - 1 - (int)blockIdx.x;  // reverse sweep
    k3_body(Sigma, p_out, ws, S_out, b0 + (bid >> 3), bid & 7);
}

// Mixed dispatch: first half of blocks = K3(group 0, reversed),
// second half = K1(group 1). Read+write streams overlap; K3's Sigma
// re-read is L3-hot from the previous dispatch.
__global__ __launch_bounds__(256)
void k13_kernel(const float* __restrict__ mu, const float* __restrict__ Sigma,
                float* __restrict__ p_out, const float* __restrict__ ws_c,
                float* __restrict__ ws, float* __restrict__ S_out) {
    if ((int)blockIdx.x < HALF_BLOCKS) {
        const int bid = HALF_BLOCKS - 1 - (int)blockIdx.x;   // reversed, g0
        k3_body(Sigma, p_out, ws_c, S_out, (bid >> 3), bid & 7);
    } else {
        const int bid = (int)blockIdx.x - HALF_BLOCKS;       // g1
        k1_body(mu, Sigma, p_out, ws, HALF_B + (bid >> 3), bid & 7);
    }
}

// ======================= fallback: round-1 fused (proven) ========
__global__ __launch_bounds__(1024, 1)
void rvsoftmax_fused(const float* __restrict__ mu,
                     const float* __restrict__ Sigma,
                     float* __restrict__ p_out,
                     float* __restrict__ S_out) {
    const int b = blockIdx.x, t = threadIdx.x, w = t >> 6, l = t & 63;
    __shared__ __align__(16) float p_lds[FDIM];
    __shared__ __align__(16) float r_lds[FDIM];
    __shared__ __align__(16) float c_lds[FDIM];
    __shared__ __align__(16) float c_stage[16][FDIM];
    __shared__ float red[16]; __shared__ float sc[2];
    float x = (t < FDIM) ? mu[(size_t)b * FDIM + t] : -__builtin_inff();
    float m = x;
    #pragma unroll
    for (int off = 32; off >= 1; off >>= 1) m = fmaxf(m, __shfl_xor(m, off));
    if (l == 0) red[w] = m;
    __syncthreads();
    if (t == 0) { float mm = red[0]; for (int j = 1; j < 16; ++j) mm = fmaxf(mm, red[j]); sc[0] = mm; }
    __syncthreads();
    const float mx = sc[0];
    float e = (t < FDIM) ? __expf(x - mx) : 0.f;
    float ssum = e;
    #pragma unroll
    for (int off = 32; off >= 1; off >>= 1) ssum += __shfl_xor(ssum, off);
    if (l == 0) red[w] = ssum;
    __syncthreads();
    if (t == 0) { float tt = 0.f; for (int j = 0; j < 16; ++j) tt += red[j]; sc[0] = tt; }
    __syncthreads();
    const float inv = 1.0f / sc[0];
    if (t < FDIM) { float pv = e * inv; p_lds[t] = pv; p_out[(size_t)b * FDIM + t] = pv; }
    __syncthreads();
    const float* Sb = Sigma + (size_t)b * S_ELEMS;
    const float4 p0 = ld4(&p_lds[4 * l]);
    const float4 p1 = ld4(&p_lds[256 + 4 * l]);
    float4 c0 = make_float4(0.f, 0.f, 0.f, 0.f), c1 = make_float4(0.f, 0.f, 0.f, 0.f);
    for (int j = 0; j < 32; ++j) {
        const int i = j * 16 + w;
        const float* row = Sb + (size_t)i * FDIM;
        const float4 a0 = ld4(&row[4 * l]); const float4 a1 = ld4(&row[256 + 4 * l]);
        const float pi = p_lds[i];
        float dot = a0.x*p0.x + a0.y*p0.y + a0.z*p0.z + a0.w*p0.w
                  + a1.x*p1.x + a1.y*p1.y + a1.z*p1.z + a1.w*p1.w;
        #pragma unroll
        for (int off = 32; off >= 1; off >>= 1) dot += __shfl_xor(dot, off);
        if (l == 0) r_lds[i] = dot;
        c0.x += pi*a0.x; c0.y += pi*a0.y; c0.z += pi*a0.z; c0.w += pi*a0.w;
        c1.x += pi*a1.x; c1.y += pi*a1.y; c1.z += pi*a1.z; c1.w += pi*a1.w;
    }
    *(float4*)&c_stage[w][4 * l] = c0;
    *(float4*)&c_stage[w][256 + 4 * l] = c1;
    __syncthreads();
    if (t < FDIM) {
        float cc = 0.f;
        #pragma unroll
        for (int j = 0; j < 16; ++j) cc += c_stage[j][t];
        c_lds[t] = cc;
    }
    __syncthreads();
    float sv = (t < FDIM) ? p_lds[t] * r_lds[t] : 0.f;
    #pragma unroll
    for (int off = 32; off >= 1; off >>= 1) sv += __shfl_xor(sv, off);
    if (l == 0) red[w] = sv;
    __syncthreads();
    if (t == 0) { float tt = 0.f; for (int j = 0; j < 16; ++j) tt += red[j]; sc[1] = tt; }
    __syncthreads();
    const float s = sc[1];
    const float4 cc0 = ld4(&c_lds[4 * l]); const float4 cc1 = ld4(&c_lds[256 + 4 * l]);
    float* Ob = S_out + (size_t)b * S_ELEMS;
    for (int j = 31; j >= 0; --j) {
        const int i = j * 16 + w;
        const float* row = Sb + (size_t)i * FDIM;
        float* orow = Ob + (size_t)i * FDIM;
        const float4 a0 = ld4(&row[4 * l]); const float4 a1 = ld4(&row[256 + 4 * l]);
        const float pi = p_lds[i];
        const float f = s - r_lds[i];
        float4 o0, o1;
        o0.x = pi*p0.x*(a0.x + (f - cc0.x)); o0.y = pi*p0.y*(a0.y + (f - cc0.y));
        o0.z = pi*p0.z*(a0.z + (f - cc0.z)); o0.w = pi*p0.w*(a0.w + (f - cc0.w));
        o1.x = pi*p1.x*(a1.x + (f - cc1.x)); o1.y = pi*p1.y*(a1.y + (f - cc1.y));
        o1.z = pi*p1.z*(a1.z + (f - cc1.z)); o1.w = pi*p1.w*(a1.w + (f - cc1.w));
        *(float4*)&orow[4 * l] = o0;
        *(float4*)&orow[256 + 4 * l] = o1;
    }
}

extern "C" void kernel_launch(void* const* d_in, const int* in_sizes, int n_in,
                              void* d_out, int out_size, void* d_ws, size_t ws_size,
                              hipStream_t stream) {
    (void)in_sizes; (void)n_in; (void)out_size;
    const float* mu    = (const float*)d_in[0];
    const float* Sigma = (const float*)d_in[1];
    float* p_out = (float*)d_out;
    float* S_out = (float*)d_out + (size_t)NB * FDIM;

    if (ws_size >= (size_t)WS_FLOATS * sizeof(float)) {
        float* ws = (float*)d_ws;
        // D1: read group 0, produce r/c-partials
        hipLaunchKernelGGL(k1_kernel, dim3(HALF_BLOCKS), dim3(256), 0, stream,
                           mu, Sigma, p_out, ws, 0);
        // D2: write group 0 (L3-hot re-read) + read group 1
        hipLaunchKernelGGL(k13_kernel, dim3(2 * HALF_BLOCKS), dim3(256), 0, stream,
                           mu, Sigma, p_out, ws, ws, S_out);
        // D3: write group 1 (L3-hot re-read)
        hipLaunchKernelGGL(k3_kernel, dim3(HALF_BLOCKS), dim3(256), 0, stream,
                           Sigma, p_out, ws, S_out, HALF_B);
    } else {
        hipLaunchKernelGGL(rvsoftmax_fused, dim3(NB), dim3(1024), 0, stream,
                           mu, Sigma, p_out, S_out);
    }
}